// Round 5
// baseline (316.335 us; speedup 1.0000x reference)
//
#include <hip/hip_runtime.h>
#include <stdint.h>

// LSTMBaseline: 2-layer, 1-step LSTM (zero init state) + decoder on MI355X.
//   h0 = lstm(x; W_ih0, b_ih0+b_hh0)   M=16384, K=512,  H=1024
//   h1 = lstm(h0; W_ih1, b_ih1+b_hh1)  K=1024
//   out = h1 @ W_dec^T + b_dec         N=512 (f32 out)
// f32 inputs -> bf16 prepass (x, GATE-MAJOR-packed W_ih{0,1}, W_dec), then
// 256-row 8-wave MFMA GEMMs with a 6-phase (gated) / 4-phase (decoder)
// interleaved schedule: per phase {counted vmcnt -> barrier -> ds_read
// subtile -> issue 1 stage unit of next K-tile -> setprio MFMA cluster}.
// Stage unit = 64 rows x 64 cols bf16 = 8KB = 1 global_load_lds/thread;
// units are issued 3-5 phases before first use. f-gate dead, W_hh dead.

typedef __attribute__((ext_vector_type(8))) __bf16 bf16x8;
typedef __attribute__((ext_vector_type(4))) float f32x4;

#define BM 256
#define BK 64

__device__ __forceinline__ unsigned short f2b(float f) {
    unsigned int x = __builtin_bit_cast(unsigned int, f);
    x = x + 0x7FFFu + ((x >> 16) & 1u);   // RNE
    return (unsigned short)(x >> 16);
}
__device__ __forceinline__ float sigf(float x) { return 1.0f / (1.0f + __expf(-x)); }
__device__ __forceinline__ float tanh_safe(float x) {
    float a = fabsf(x);
    float e = __expf(-2.0f * a);
    float t = (1.0f - e) / (1.0f + e);
    return x < 0.0f ? -t : t;
}

__device__ __forceinline__ void cvt8(const float* __restrict__ s,
                                     unsigned short* __restrict__ d) {
    f32x4 lo = *reinterpret_cast<const f32x4*>(s);
    f32x4 hi = *reinterpret_cast<const f32x4*>(s + 4);
    __attribute__((ext_vector_type(8))) unsigned short v;
    v[0] = f2b(lo[0]); v[1] = f2b(lo[1]); v[2] = f2b(lo[2]); v[3] = f2b(lo[3]);
    v[4] = f2b(hi[0]); v[5] = f2b(hi[1]); v[6] = f2b(hi[2]); v[7] = f2b(hi[3]);
    *reinterpret_cast<__attribute__((ext_vector_type(8))) unsigned short*>(d) = v;
}

__device__ __forceinline__ void gload16(const unsigned short* g, unsigned short* l) {
    __builtin_amdgcn_global_load_lds(
        (const __attribute__((address_space(1))) void*)g,
        (__attribute__((address_space(3))) void*)l,
        16, 0, 0);
}

#define VMW(n) asm volatile("s_waitcnt vmcnt(" #n ")" ::: "memory")
#define BARS()                                \
    do {                                      \
        __builtin_amdgcn_s_barrier();         \
        __builtin_amdgcn_sched_barrier(0);    \
    } while (0)

// ---- pre-pass: f32 -> bf16 linear convert ---------------------------------
__global__ __launch_bounds__(256) void cvt_lin(const float* __restrict__ s,
                                               unsigned short* __restrict__ d,
                                               int n8) {
    int stride = gridDim.x * blockDim.x;
    for (int c = blockIdx.x * blockDim.x + threadIdx.x; c < n8; c += stride)
        cvt8(s + (size_t)c * 8, d + (size_t)c * 8);
}

// ---- pre-pass: gate-major pack W (4H x K f32) -> (H/64 x 192 x K) bf16 ----
// Group = 64 h-cols. Packed row r in group: r = gate*64 + (wc*16+i);
// hcol = group*64 + (r&63); src row = {0,2H,3H}[gate] + hcol.
__global__ __launch_bounds__(256) void pack_w(const float* __restrict__ W,
                                              unsigned short* __restrict__ d,
                                              int K8, int H, int n8) {
    int stride = gridDim.x * blockDim.x;
    for (int c = blockIdx.x * blockDim.x + threadIdx.x; c < n8; c += stride) {
        int dstRow = c / K8, kc = c - dstRow * K8;
        int group = dstRow / 192, r = dstRow - group * 192;
        int g = r >> 6;
        int goff = (g == 0) ? 0 : (g + 1);       // {i,g,o} -> rows {0,2H,3H}
        int hcol = group * 64 + (r & 63);
        cvt8(W + ((size_t)(goff * H + hcol) * K8 + kc) * 8, d + (size_t)c * 8);
    }
}

// ---- fused GEMM: 256-row tile, 8 waves (2M x 4N), phase-interleaved -------
// GATED=1 (NF=3): B tile 192 rows gate-major; fragment g == gate; per-lane
//   activation epilogue -> bf16 h. GATED=0 (NF=2): B tile 128 rows = out
//   cols n0..n0+127 linear; f32 out + bias.
template <int GATED, int NF>
__global__ __launch_bounds__(512, 2) void gemm_fused(
    const unsigned short* __restrict__ A,   // M x K bf16
    const unsigned short* __restrict__ Wp,  // packed/linear bf16, rows x K
    const float* __restrict__ b0,
    const float* __restrict__ b1,
    void* __restrict__ Ov,
    int M, int K, int N, int NBX)
{
    constexpr int BROWS = NF * 64;          // B tile rows (192 / 128)
    constexpr int NU    = 4 + NF;           // stage units per K-tile
    constexpr int ONB   = GATED ? 64 : 128; // output cols per block

    __shared__ __align__(16) unsigned short sA[2][BM * BK];
    __shared__ __align__(16) unsigned short sB[2][BROWS * BK];

    const int tid  = threadIdx.x;
    const int lane = tid & 63;
    const int w    = tid >> 6;
    const int wr   = w >> 2, wc = w & 3;
    const int l16  = lane & 15, hi8 = lane >> 4;
    const int x7   = l16 & 7;

    // Bijective XCD swizzle (grids are multiples of 8).
    const int cpx  = gridDim.x >> 3;
    const int orig = blockIdx.x;
    const int rid  = (orig & 7) * cpx + (orig >> 3);
    const int bx   = rid % NBX;
    const int by   = rid / NBX;
    const int row0 = by * BM;
    const int n0   = bx * ONB;

    // Stage pointers: unit u covers rows [u*64, u*64+64) of its tile; thread
    // covers (row r0, k-slot sl), global source pre-swizzled (ls = sl^(r0&7)),
    // LDS dest linear (unit base + tid*16B) per global_load_lds rules.
    const int r0 = tid >> 3, sl = tid & 7;
    const int ls = sl ^ (r0 & 7);
    const unsigned short* pU[NU];
#pragma unroll
    for (int u = 0; u < 4; ++u)
        pU[u] = A + (size_t)(row0 + u * 64 + r0) * K + ls * 8;
#pragma unroll
    for (int u = 0; u < NF; ++u)
        pU[4 + u] = Wp + (size_t)(bx * BROWS + u * 64 + r0) * K + ls * 8;

    auto STG = [&](int u, int buf) {
        unsigned short* dst = (u < 4) ? &sA[buf][u * 4096 + tid * 8]
                                      : &sB[buf][(u - 4) * 4096 + tid * 8];
        gload16(pU[u], dst);
        pU[u] += BK;
    };

    bf16x8 av[4][2];
    auto LDAV = [&](int h, int buf) {
#pragma unroll
        for (int mm = 0; mm < 4; ++mm) {
            int row = wr * 128 + (h * 4 + mm) * 16 + l16;
#pragma unroll
            for (int ks = 0; ks < 2; ++ks) {
                int ps = (ks * 4 + hi8) ^ x7;
                av[mm][ks] = *reinterpret_cast<const bf16x8*>(
                    &sA[buf][row * BK + ps * 8]);
            }
        }
    };
    bf16x8 bv0, bv1;
    auto LDBV = [&](int g, int buf) {
        int row = g * 64 + wc * 16 + l16;
        bv0 = *reinterpret_cast<const bf16x8*>(
            &sB[buf][row * BK + ((0 + hi8) ^ x7) * 8]);
        bv1 = *reinterpret_cast<const bf16x8*>(
            &sB[buf][row * BK + ((4 + hi8) ^ x7) * 8]);
    };

    f32x4 acc[8][NF];
#pragma unroll
    for (int m = 0; m < 8; ++m)
#pragma unroll
        for (int n = 0; n < NF; ++n)
            acc[m][n] = (f32x4){0.f, 0.f, 0.f, 0.f};

    auto MM = [&](int h, int g) {
        __builtin_amdgcn_s_setprio(1);
#pragma unroll
        for (int mm = 0; mm < 4; ++mm) {
            acc[h * 4 + mm][g] = __builtin_amdgcn_mfma_f32_16x16x32_bf16(
                av[mm][0], bv0, acc[h * 4 + mm][g], 0, 0, 0);
            acc[h * 4 + mm][g] = __builtin_amdgcn_mfma_f32_16x16x32_bf16(
                av[mm][1], bv1, acc[h * 4 + mm][g], 0, 0, 0);
        }
        __builtin_amdgcn_s_setprio(0);
    };

    const int NT = K >> 6;   // >= 2 always (8 or 16)

    // Prologue: issue tile 0's units into buf 0, in the canonical FIFO order.
    if constexpr (NF == 3) {
        STG(4, 0); STG(0, 0); STG(2, 0); STG(5, 0); STG(6, 0); STG(1, 0); STG(3, 0);
    } else {
        STG(4, 0); STG(0, 0); STG(2, 0); STG(5, 0); STG(1, 0); STG(3, 0);
    }

    for (int t = 0; t < NT; ++t) {
        const int cb = t & 1, nb = cb ^ 1;
        const bool st = (t + 1 < NT);   // issue tile t+1's units this tile

        if constexpr (NF == 3) {
            // Issue order for tile t+1: [b0,a0,a2,b1,b2,a1,a3] spread over
            // phases 0..5. First-need of tile t: ph0:{b0,a0,a2} ph1:{b1}
            // ph2:{b2} ph3:{a1,a3}. Steady waits 4/4/4/3; last 4/3/2/0.
            // ph0 (lo, gate0)
            VMW(4); BARS();
            LDAV(0, cb);
            if (st) STG(4, nb);
            LDBV(0, cb); MM(0, 0);
            // ph1 (lo, gate1)
            if (st) { VMW(4); } else { VMW(3); }
            BARS();
            if (st) STG(0, nb);
            LDBV(1, cb); MM(0, 1);
            // ph2 (lo, gate2)
            if (st) { VMW(4); } else { VMW(2); }
            BARS();
            if (st) STG(2, nb);
            LDBV(2, cb); MM(0, 2);
            // ph3 (hi, gate0)
            if (st) { VMW(3); } else { VMW(0); }
            BARS();
            LDAV(1, cb);
            if (st) STG(5, nb);
            LDBV(0, cb); MM(1, 0);
            // ph4 (hi, gate1)
            BARS();
            if (st) STG(6, nb);
            LDBV(1, cb); MM(1, 1);
            // ph5 (hi, gate2)
            BARS();
            if (st) { STG(1, nb); STG(3, nb); }
            LDBV(2, cb); MM(1, 2);
        } else {
            // Issue order: [b0,a0,a2,b1,a1,a3] over phases 0..3 (2,2,1,1).
            // First-need: ph0:{b0,a0,a2} ph1:{b1} ph2:{a1,a3}.
            // Steady waits 3/4/4; last 3/2/0.
            // ph0 (lo, n0)
            VMW(3); BARS();
            LDAV(0, cb);
            if (st) { STG(4, nb); STG(0, nb); }
            LDBV(0, cb); MM(0, 0);
            // ph1 (lo, n1)
            if (st) { VMW(4); } else { VMW(2); }
            BARS();
            if (st) { STG(2, nb); STG(5, nb); }
            LDBV(1, cb); MM(0, 1);
            // ph2 (hi, n0)
            if (st) { VMW(4); } else { VMW(0); }
            BARS();
            LDAV(1, cb);
            if (st) STG(1, nb);
            LDBV(0, cb); MM(1, 0);
            // ph3 (hi, n1)
            BARS();
            if (st) STG(3, nb);
            LDBV(1, cb); MM(1, 1);
        }
    }

    // ---- epilogue ----
    if constexpr (GATED) {
        unsigned short* O = (unsigned short*)Ov;
        const int hcol = n0 + wc * 16 + l16;    // fragment g == gate
        const float bi = b0[hcol]         + b1[hcol];
        const float bg = b0[2 * N + hcol] + b1[2 * N + hcol];
        const float bo = b0[3 * N + hcol] + b1[3 * N + hcol];
#pragma unroll
        for (int m = 0; m < 8; ++m) {
            int rbase = row0 + wr * 128 + m * 16 + hi8 * 4;
#pragma unroll
            for (int q = 0; q < 4; ++q) {
                float iv = sigf(acc[m][0][q] + bi);
                float gv = tanh_safe(acc[m][1][q] + bg);
                float ov = sigf(acc[m][2][q] + bo);
                float h  = ov * tanh_safe(iv * gv);
                O[(size_t)(rbase + q) * N + hcol] = f2b(h);
            }
        }
    } else {
        float* O = (float*)Ov;
#pragma unroll
        for (int n = 0; n < NF; ++n) {
            int col = n0 + n * 64 + wc * 16 + l16;  // B row r <-> out col n0+r
            float bias = b0[col];
#pragma unroll
            for (int m = 0; m < 8; ++m) {
                int rbase = row0 + wr * 128 + m * 16 + hi8 * 4;
#pragma unroll
                for (int q = 0; q < 4; ++q)
                    O[(size_t)(rbase + q) * N + col] = acc[m][n][q] + bias;
            }
        }
    }
}

extern "C" void kernel_launch(void* const* d_in, const int* in_sizes, int n_in,
                              void* d_out, int out_size, void* d_ws, size_t ws_size,
                              hipStream_t stream) {
    constexpr int M = 16384, D = 512, H = 1024;

    const float* x    = (const float*)d_in[0];
    const float* Wih0 = (const float*)d_in[1];
    // d_in[2] = W_hh0: unused (h0 = 0)
    const float* bih0 = (const float*)d_in[3];
    const float* bhh0 = (const float*)d_in[4];
    const float* Wih1 = (const float*)d_in[5];
    // d_in[6] = W_hh1: unused
    const float* bih1 = (const float*)d_in[7];
    const float* bhh1 = (const float*)d_in[8];
    const float* Wdec = (const float*)d_in[9];
    const float* bdec = (const float*)d_in[10];

    const size_t szH = (size_t)M * H * 2;          // 33.5 MB
    const size_t sw0 = (size_t)3 * H * D * 2;      // 3.1 MB
    const size_t sw1 = (size_t)3 * H * H * 2;      // 6.3 MB

    unsigned short* h0 = (unsigned short*)d_ws;
    unsigned short* h1 = (unsigned short*)((char*)d_ws + szH);
    unsigned short* xb = h1;                       // alias: dead before L1 writes h1
    unsigned short* wp0   = (unsigned short*)((char*)d_ws + 2 * szH);
    unsigned short* wp1   = (unsigned short*)((char*)wp0 + sw0);
    unsigned short* wdecb = (unsigned short*)((char*)wp1 + sw1);

    cvt_lin<<<2048, 256, 0, stream>>>(x, xb, M * D / 8);
    pack_w <<<768,  256, 0, stream>>>(Wih0, wp0, D / 8, H, 3 * H * D / 8);
    pack_w <<<1536, 256, 0, stream>>>(Wih1, wp1, H / 8, H, 3 * H * H / 8);
    cvt_lin<<<256,  256, 0, stream>>>(Wdec, wdecb, D * H / 8);

    // layer 0: K=512; grid = (H/64) x (M/256) = 1024 blocks
    gemm_fused<1, 3><<<dim3((H / 64) * (M / BM)), 512, 0, stream>>>(
        xb, wp0, bih0, bhh0, h0, M, D, H, H / 64);
    // layer 1: K=1024
    gemm_fused<1, 3><<<dim3((H / 64) * (M / BM)), 512, 0, stream>>>(
        h0, wp1, bih1, bhh1, h1, M, H, H, H / 64);
    // decoder: N=512; grid = (D/128) x (M/256) = 256 blocks
    gemm_fused<0, 2><<<dim3((D / 128) * (M / BM)), 512, 0, stream>>>(
        h1, wdecb, bdec, nullptr, (float*)d_out, M, H, D, D / 128);
}

// Round 6
// 215.563 us; speedup vs baseline: 1.4675x; 1.4675x over previous
//
#include <hip/hip_runtime.h>
#include <stdint.h>

// LSTMBaseline: 2-layer, 1-step LSTM (zero init state) + decoder on MI355X.
//   h0 = lstm(x; W_ih0, b_ih0+b_hh0)   M=16384, K=512,  H=1024
//   h1 = lstm(h0; W_ih1, b_ih1+b_hh1)  K=1024
//   out = h1 @ W_dec^T + b_dec         N=512 (f32 out)
// f32 inputs -> bf16 prepass (x, gate-packed W_ih{0,1}, W_dec), then simple
// 2-barrier MFMA GEMMs (round-3 structure, which beat both deep-pipeline
// attempts) with DENSER tiles: gated 128x64-out (B=192 rows, acc[4][6],
// 4.8 MFMA/KB staged, 3 blocks/CU); decoder m97 128x128 (acc[4][4]).
// f-gate dead (c0=0), W_hh dead (h0=0).

typedef __attribute__((ext_vector_type(8))) __bf16 bf16x8;
typedef __attribute__((ext_vector_type(4))) float f32x4;

#define BM 128
#define BK 64

__device__ __forceinline__ unsigned short f2b(float f) {
    unsigned int x = __builtin_bit_cast(unsigned int, f);
    x = x + 0x7FFFu + ((x >> 16) & 1u);   // RNE
    return (unsigned short)(x >> 16);
}
__device__ __forceinline__ float sigf(float x) { return 1.0f / (1.0f + __expf(-x)); }
__device__ __forceinline__ float tanh_safe(float x) {
    float a = fabsf(x);
    float e = __expf(-2.0f * a);
    float t = (1.0f - e) / (1.0f + e);
    return x < 0.0f ? -t : t;
}

__device__ __forceinline__ void cvt8(const float* __restrict__ s,
                                     unsigned short* __restrict__ d) {
    f32x4 lo = *reinterpret_cast<const f32x4*>(s);
    f32x4 hi = *reinterpret_cast<const f32x4*>(s + 4);
    __attribute__((ext_vector_type(8))) unsigned short v;
    v[0] = f2b(lo[0]); v[1] = f2b(lo[1]); v[2] = f2b(lo[2]); v[3] = f2b(lo[3]);
    v[4] = f2b(hi[0]); v[5] = f2b(hi[1]); v[6] = f2b(hi[2]); v[7] = f2b(hi[3]);
    *reinterpret_cast<__attribute__((ext_vector_type(8))) unsigned short*>(d) = v;
}

__device__ __forceinline__ void gload16(const unsigned short* g, unsigned short* l) {
    __builtin_amdgcn_global_load_lds(
        (const __attribute__((address_space(1))) void*)g,
        (__attribute__((address_space(3))) void*)l,
        16, 0, 0);
}

// ---- pre-pass: f32 -> bf16 linear convert ---------------------------------
__global__ __launch_bounds__(256) void cvt_lin(const float* __restrict__ s,
                                               unsigned short* __restrict__ d,
                                               int n8) {
    int stride = gridDim.x * blockDim.x;
    for (int c = blockIdx.x * blockDim.x + threadIdx.x; c < n8; c += stride)
        cvt8(s + (size_t)c * 8, d + (size_t)c * 8);
}

// ---- pre-pass: gate-pack W (4H x K f32) -> (H/64 groups x 192 x K) bf16 ----
// Group G covers out-cols [G*64, G*64+64). Packed row r in group:
// r = wc*96 + (hsub*3 + gate)*16 + i; hcol = G*64 + wc*32 + hsub*16 + i;
// src row = {0,2H,3H}[gate] + hcol. Matches the GEMM's bv[n] read order
// (wave wc, fragment n = hsub*3+gate).
__global__ __launch_bounds__(256) void pack_w(const float* __restrict__ W,
                                              unsigned short* __restrict__ d,
                                              int K8, int H, int n8) {
    int stride = gridDim.x * blockDim.x;
    for (int c = blockIdx.x * blockDim.x + threadIdx.x; c < n8; c += stride) {
        int dstRow = c / K8, kc = c - dstRow * K8;
        int G = dstRow / 192, r = dstRow - G * 192;
        int wc = r / 96, rr = r - wc * 96;
        int n = rr >> 4, i = rr & 15;
        int hsub = n / 3, gate = n - hsub * 3;
        int goff = (gate == 0) ? 0 : (gate + 1);   // {i,g,o} -> {0,2H,3H}
        int hcol = G * 64 + wc * 32 + hsub * 16 + i;
        cvt8(W + ((size_t)(goff * H + hcol) * K8 + kc) * 8, d + (size_t)c * 8);
    }
}

// ---- fused GEMM: 128-row tile, 4 waves (2Mx2N), 2-barrier K-loop ----------
// GATED=1: B 192 rows (packed gate-major per 64 out-cols); wave acc[4][6]
//   (n = hsub*3+gate); per-lane activation epilogue -> bf16 h (2 cols/lane).
// GATED=0: m97-style 128x128; B rows = out cols linear; f32 out + bias.
template <int GATED>
__global__ __launch_bounds__(256, 3) void gemm_fused(
    const unsigned short* __restrict__ A,   // M x K bf16
    const unsigned short* __restrict__ Wp,  // packed/linear bf16, rows x K
    const float* __restrict__ b0,
    const float* __restrict__ b1,
    void* __restrict__ Ov,
    int M, int K, int N, int NBX)
{
    constexpr int NFR   = GATED ? 6 : 4;     // col fragments per wave
    constexpr int BROWS = GATED ? 192 : 128; // B tile rows
    constexpr int WCS   = GATED ? 96 : 64;   // B rows per wave-col group
    constexpr int ONB   = GATED ? 64 : 128;  // out cols per block
    constexpr int NBCH  = BROWS / 32;        // B gloads per thread (6 / 4)

    __shared__ __align__(16) unsigned short sA[BM * BK];
    __shared__ __align__(16) unsigned short sB[BROWS * BK];

    const int tid  = threadIdx.x;
    const int lane = tid & 63;
    const int w    = tid >> 6;
    const int wr   = w >> 1, wc = w & 1;
    const int l16  = lane & 15, hi8 = lane >> 4;

    // Bijective XCD swizzle (grids are multiples of 8).
    const int cpx  = gridDim.x >> 3;
    const int orig = blockIdx.x;
    const int rid  = (orig & 7) * cpx + (orig >> 3);
    const int bx   = rid % NBX;
    const int by   = rid / NBX;
    const int row0 = by * BM;
    const int n0   = bx * ONB;

    // Staging: chunk i covers row (tid>>3)+i*32, k-slot sl=tid&7. Global
    // source pre-swizzled (ls = sl^(row&7)); LDS dest linear (tid*8+i*2048).
    // Offsets are linear in i (stride 32*K) -> 2 base regs total.
    const int r0 = tid >> 3, sl = tid & 7;
    const int ls = sl ^ (r0 & 7);              // r0&7 == row&7 (stride 32)
    const unsigned int strd = 32u * (unsigned)K;
    unsigned int offA = (unsigned)(row0 + r0) * (unsigned)K + ls * 8;
    unsigned int offB = (unsigned)(GATED ? bx * BROWS + r0 : n0 + r0)
                        * (unsigned)K + ls * 8;

    f32x4 acc[4][NFR];
#pragma unroll
    for (int m = 0; m < 4; ++m)
#pragma unroll
        for (int n = 0; n < NFR; ++n)
            acc[m][n] = (f32x4){0.f, 0.f, 0.f, 0.f};

    for (int k0 = 0; k0 < K; k0 += BK) {
#pragma unroll
        for (int i = 0; i < 4; ++i)
            gload16(A + offA + i * strd + k0, sA + tid * 8 + i * 2048);
#pragma unroll
        for (int i = 0; i < NBCH; ++i)
            gload16(Wp + offB + i * strd + k0, sB + tid * 8 + i * 2048);
        __syncthreads();   // drains vmcnt: staged tile visible

#pragma unroll
        for (int ks = 0; ks < 2; ++ks) {
            bf16x8 av[4], bv[NFR];
#pragma unroll
            for (int m = 0; m < 4; ++m) {
                int row = wr * 64 + m * 16 + l16;
                int ps = (ks * 4 + hi8) ^ (row & 7);
                av[m] = *reinterpret_cast<const bf16x8*>(sA + row * BK + ps * 8);
            }
#pragma unroll
            for (int n = 0; n < NFR; ++n) {
                int row = wc * WCS + n * 16 + l16;
                int ps = (ks * 4 + hi8) ^ (row & 7);
                bv[n] = *reinterpret_cast<const bf16x8*>(sB + row * BK + ps * 8);
            }
#pragma unroll
            for (int m = 0; m < 4; ++m)
#pragma unroll
                for (int n = 0; n < NFR; ++n)
                    acc[m][n] = __builtin_amdgcn_mfma_f32_16x16x32_bf16(
                        av[m], bv[n], acc[m][n], 0, 0, 0);
        }
        __syncthreads();   // protect LDS before next stage
    }

    // ---- epilogue ----
    if constexpr (GATED) {
        unsigned short* O = (unsigned short*)Ov;
#pragma unroll
        for (int hsub = 0; hsub < 2; ++hsub) {
            const int hcol = n0 + wc * 32 + hsub * 16 + l16;
            const float bi = b0[hcol]         + b1[hcol];
            const float bg = b0[2 * N + hcol] + b1[2 * N + hcol];
            const float bo = b0[3 * N + hcol] + b1[3 * N + hcol];
#pragma unroll
            for (int m = 0; m < 4; ++m) {
                int rbase = row0 + wr * 64 + m * 16 + hi8 * 4;
#pragma unroll
                for (int q = 0; q < 4; ++q) {
                    float iv = sigf(acc[m][hsub * 3 + 0][q] + bi);
                    float gv = tanh_safe(acc[m][hsub * 3 + 1][q] + bg);
                    float ov = sigf(acc[m][hsub * 3 + 2][q] + bo);
                    float h  = ov * tanh_safe(iv * gv);
                    O[(size_t)(rbase + q) * N + hcol] = f2b(h);
                }
            }
        }
    } else {
        float* O = (float*)Ov;
#pragma unroll
        for (int n = 0; n < NFR; ++n) {
            int col = n0 + wc * WCS + n * 16 + l16;
            float bias = b0[col];
#pragma unroll
            for (int m = 0; m < 4; ++m) {
                int rbase = row0 + wr * 64 + m * 16 + hi8 * 4;
#pragma unroll
                for (int q = 0; q < 4; ++q)
                    O[(size_t)(rbase + q) * N + col] = acc[m][n][q] + bias;
            }
        }
    }
}

extern "C" void kernel_launch(void* const* d_in, const int* in_sizes, int n_in,
                              void* d_out, int out_size, void* d_ws, size_t ws_size,
                              hipStream_t stream) {
    constexpr int M = 16384, D = 512, H = 1024;

    const float* x    = (const float*)d_in[0];
    const float* Wih0 = (const float*)d_in[1];
    // d_in[2] = W_hh0: unused (h0 = 0)
    const float* bih0 = (const float*)d_in[3];
    const float* bhh0 = (const float*)d_in[4];
    const float* Wih1 = (const float*)d_in[5];
    // d_in[6] = W_hh1: unused
    const float* bih1 = (const float*)d_in[7];
    const float* bhh1 = (const float*)d_in[8];
    const float* Wdec = (const float*)d_in[9];
    const float* bdec = (const float*)d_in[10];

    const size_t szH = (size_t)M * H * 2;          // 33.5 MB
    const size_t sw0 = (size_t)3 * H * D * 2;      // 3.1 MB
    const size_t sw1 = (size_t)3 * H * H * 2;      // 6.3 MB

    unsigned short* h0 = (unsigned short*)d_ws;
    unsigned short* h1 = (unsigned short*)((char*)d_ws + szH);
    unsigned short* xb = h1;                       // alias: dead before L1 writes h1
    unsigned short* wp0   = (unsigned short*)((char*)d_ws + 2 * szH);
    unsigned short* wp1   = (unsigned short*)((char*)wp0 + sw0);
    unsigned short* wdecb = (unsigned short*)((char*)wp1 + sw1);

    cvt_lin<<<2048, 256, 0, stream>>>(x, xb, M * D / 8);
    pack_w <<<768,  256, 0, stream>>>(Wih0, wp0, D / 8, H, 3 * H * D / 8);
    pack_w <<<1536, 256, 0, stream>>>(Wih1, wp1, H / 8, H, 3 * H * H / 8);
    cvt_lin<<<256,  256, 0, stream>>>(Wdec, wdecb, D * H / 8);

    // layer 0: K=512; grid = (H/64) x (M/128) = 16 x 128 = 2048 blocks
    gemm_fused<1><<<dim3((H / 64) * (M / BM)), 256, 0, stream>>>(
        xb, wp0, bih0, bhh0, h0, M, D, H, H / 64);
    // layer 1: K=1024
    gemm_fused<1><<<dim3((H / 64) * (M / BM)), 256, 0, stream>>>(
        h0, wp1, bih1, bhh1, h1, M, H, H, H / 64);
    // decoder: N=512; grid = (D/128) x (M/128) = 4 x 128 = 512 blocks
    gemm_fused<0><<<dim3((D / 128) * (M / BM)), 256, 0, stream>>>(
        h1, wdecb, bdec, nullptr, (float*)d_out, M, H, D, D / 128);
}